// Round 11
// baseline (6757.276 us; speedup 1.0000x reference)
//
#include <hip/hip_runtime.h>

typedef __attribute__((ext_vector_type(8))) short s16x8;
typedef __attribute__((ext_vector_type(4))) float fx4;

static __device__ __forceinline__ unsigned short f2bf(float f){
  unsigned u = __float_as_uint(f);
  return (unsigned short)((u + 0x7fffu + ((u>>16)&1u)) >> 16);   // RNE
}
static __device__ __forceinline__ float bf2f(unsigned short s){
  return __uint_as_float(((unsigned)s)<<16);
}
// fast tanh: 1 - 2/(e^{2x}+1). __expf + v_rcp_f32 ~6 ops vs libm tanhf.
// Saturates correctly (x>>0 -> 1, x<<0 -> -1); err ~1e-6 << bf16 ulp.
static __device__ __forceinline__ float tanh_fast(float x){
  float e = __expf(2.0f*x);
  return 1.0f - 2.0f*__builtin_amdgcn_rcpf(e + 1.0f);
}

// ---------------------------------------------------------------- W_out -> bf16
__global__ void k_cvt_wout(const float* __restrict__ w, unsigned short* __restrict__ o){
  int g = blockIdx.x*256 + threadIdx.x;
  int idx = g*4;
  float4 f = *(const float4*)(w + idx);
  unsigned u0 = (unsigned)f2bf(f.x) | ((unsigned)f2bf(f.y)<<16);
  unsigned u1 = (unsigned)f2bf(f.z) | ((unsigned)f2bf(f.w)<<16);
  *(uint2*)(o + idx) = make_uint2(u0, u1);
}

// ---------------------------------------------------------------- GEMM1: xp = x@W_ih^T + (b_ih+b_hh)
__global__ __launch_bounds__(256) void k_gemm_xp(
    const float* __restrict__ X, const float* __restrict__ Wih,
    const float* __restrict__ bih, const float* __restrict__ bhh,
    unsigned short* __restrict__ XP){
  __shared__ unsigned short As[128][40];
  __shared__ unsigned short Bs[128][40];
  const int bm = blockIdx.x, bn = blockIdx.y;
  const int tid = threadIdx.x, w = tid>>6, l = tid&63;
  const int wm = w>>1, wn = w&1;
  const int m0 = bm*128, n0 = bn*128;
  fx4 acc[4][4] = {};
  for (int kb = 0; kb < 512; kb += 32){
    #pragma unroll
    for (int q=0;q<4;q++){
      int f = tid + q*256;
      int row = f>>3, c4 = (f&7)*4;
      float4 v = *(const float4*)(X + (m0+row)*512 + kb + c4);
      unsigned u0 = (unsigned)f2bf(v.x) | ((unsigned)f2bf(v.y)<<16);
      unsigned u1 = (unsigned)f2bf(v.z) | ((unsigned)f2bf(v.w)<<16);
      *(uint2*)&As[row][c4] = make_uint2(u0,u1);
    }
    #pragma unroll
    for (int q=0;q<4;q++){
      int f = tid + q*256;
      int row = f>>3, c4 = (f&7)*4;
      float4 v = *(const float4*)(Wih + (n0+row)*512 + kb + c4);
      unsigned u0 = (unsigned)f2bf(v.x) | ((unsigned)f2bf(v.y)<<16);
      unsigned u1 = (unsigned)f2bf(v.z) | ((unsigned)f2bf(v.w)<<16);
      *(uint2*)&Bs[row][c4] = make_uint2(u0,u1);
    }
    __syncthreads();
    const int kbase = (l>>4)*8;
    s16x8 a[4], b[4];
    #pragma unroll
    for (int mt=0;mt<4;mt++) a[mt] = *(const s16x8*)&As[wm*64 + mt*16 + (l&15)][kbase];
    #pragma unroll
    for (int nt=0;nt<4;nt++) b[nt] = *(const s16x8*)&Bs[wn*64 + nt*16 + (l&15)][kbase];
    #pragma unroll
    for (int mt=0;mt<4;mt++)
      #pragma unroll
      for (int nt=0;nt<4;nt++)
        acc[mt][nt] = __builtin_amdgcn_mfma_f32_16x16x32_bf16(a[mt], b[nt], acc[mt][nt], 0,0,0);
    __syncthreads();
  }
  #pragma unroll
  for (int nt=0;nt<4;nt++){
    int n = n0 + wn*64 + nt*16 + (l&15);
    float bias = bih[n] + bhh[n];
    #pragma unroll
    for (int mt=0;mt<4;mt++){
      #pragma unroll
      for (int r=0;r<4;r++){
        int grow = m0 + wm*64 + mt*16 + (l>>4)*4 + r;   // = b*1024 + t
        int bb = grow >> 10, t = grow & 1023;
        XP[(t*64 + bb)*1024 + n] = f2bf(acc[mt][nt][r] + bias);
      }
    }
  }
}

// ---------------------------------------------------------------- recurrence
// R9 poison-poll base (best measured: 2540us), three latency cuts:
//  (1) xp prefetched ONE STEP AHEAD, issued after the stage barrier -> its
//      HBM latency (~900cy) overlaps MFMA/epilogue instead of being
//      serialized into every poll iteration's vmcnt(0).
//  (2) only waves 0-3 poll/stage (64B/thread): halves LLC poll traffic and
//      the barrier-tail population; waves 4-7 wait at the barrier.
//  (3) tanh_fast epilogue; staging map (row=tid&7, chunk=tid>>3) makes LDS
//      writes 2-way (free) instead of 16-way conflicted.
// Protocol unchanged (R9-proven): HS pre-poisoned 0xFFFF (bf16 NaN, tanh
// never produces it); write-once addresses; sc0+sc1 poll loads read the LLC
// every iteration; data self-announces. Placement-independent, flag-free,
// deadlock-impossible.
__global__ __launch_bounds__(512) void k_rnn(
    const float* __restrict__ Whh, const unsigned short* __restrict__ XP,
    unsigned short* __restrict__ HS){
  __shared__ unsigned short hlds[8][1032];
  const int wg = blockIdx.x;
  const int gi = wg & 7;            // batch-group (8 rows)
  const int gj = wg >> 3;           // col block (128 cols)
  const int bi = gi*8, cj = gj*128;
  const int tid = threadIdx.x, w = tid>>6, l = tid&63;
  const int kbase = (l>>4)*8;

  // --- W_hh slice as resident MFMA B-fragments (128 VGPR/lane) ---
  const int col = cj + w*16 + (l&15);
  s16x8 wf[32];
  #pragma unroll
  for (int kk=0; kk<32; kk++){
    const float* p = Whh + col*1024 + kk*32 + kbase;
    float4 v0 = *(const float4*)p;
    float4 v1 = *(const float4*)(p+4);
    s16x8 s;
    s[0]=(short)f2bf(v0.x); s[1]=(short)f2bf(v0.y); s[2]=(short)f2bf(v0.z); s[3]=(short)f2bf(v0.w);
    s[4]=(short)f2bf(v1.x); s[5]=(short)f2bf(v1.y); s[6]=(short)f2bf(v1.z); s[7]=(short)f2bf(v1.w);
    wf[kk]=s;
  }

  const int ecol = cj + w*16 + (l&15);

  // --- step 0: h0 = tanh(xp_0) for this WG's 8 rows x 128 cols ---
  {
    int e = tid*2;
    int row = e>>7, c = e&127;
    unsigned short h0 = f2bf(tanh_fast(bf2f(XP[(bi+row)*1024 + cj + c])));
    unsigned short h1 = f2bf(tanh_fast(bf2f(XP[(bi+row)*1024 + cj + c + 1])));
    unsigned pk = (unsigned)h0 | ((unsigned)h1<<16);
    __hip_atomic_store((unsigned*)&HS[((bi+row)*1024 + 0)*1024 + cj + c], pk,
                       __ATOMIC_RELAXED, __HIP_MEMORY_SCOPE_AGENT);
  }

  // --- prologue: prefetch xp for s=1 (consumed in step 1's epilogue) ---
  float xc0=0.f, xc1=0.f, xc2=0.f, xc3=0.f;
  if (l < 32){
    xc0 = bf2f(XP[(64 + bi + (l>>4)*4 + 0)*1024 + ecol]);
    xc1 = bf2f(XP[(64 + bi + (l>>4)*4 + 1)*1024 + ecol]);
    xc2 = bf2f(XP[(64 + bi + (l>>4)*4 + 2)*1024 + ecol]);
    xc3 = bf2f(XP[(64 + bi + (l>>4)*4 + 3)*1024 + ecol]);
  }

  const int srow = tid & 7;         // staging: row 0..7
  const int sc32 = (tid>>3)*32;     // 32-short (64B) chunk within row (tid<256)

  for (int s=1; s<1024; ++s){
    // --- poison-poll + stage h_{s-1}: waves 0-3 only, 64B/thread ---
    if (tid < 256){
      const unsigned short* rowp = HS + ((bi+srow)*1024 + (s-1))*1024 + sc32;
      uint4 v0, v1, v2, v3;
      for(;;){
        asm volatile(
          "global_load_dwordx4 %0, %4, off sc0 sc1\n\t"
          "global_load_dwordx4 %1, %4, off offset:16 sc0 sc1\n\t"
          "global_load_dwordx4 %2, %4, off offset:32 sc0 sc1\n\t"
          "global_load_dwordx4 %3, %4, off offset:48 sc0 sc1\n\t"
          "s_waitcnt vmcnt(0)"
          : "=&v"(v0), "=&v"(v1), "=&v"(v2), "=&v"(v3)
          : "v"(rowp) : "memory");
        unsigned bad = 0u;
        #pragma unroll
        for (int j=0;j<4;j++){
          unsigned u = ((unsigned*)&v0)[j];
          bad |= (unsigned)((u & 0xFFFFu) == 0xFFFFu) | (unsigned)(u >= 0xFFFF0000u);
        }
        #pragma unroll
        for (int j=0;j<4;j++){
          unsigned u = ((unsigned*)&v1)[j];
          bad |= (unsigned)((u & 0xFFFFu) == 0xFFFFu) | (unsigned)(u >= 0xFFFF0000u);
        }
        #pragma unroll
        for (int j=0;j<4;j++){
          unsigned u = ((unsigned*)&v2)[j];
          bad |= (unsigned)((u & 0xFFFFu) == 0xFFFFu) | (unsigned)(u >= 0xFFFF0000u);
        }
        #pragma unroll
        for (int j=0;j<4;j++){
          unsigned u = ((unsigned*)&v3)[j];
          bad |= (unsigned)((u & 0xFFFFu) == 0xFFFFu) | (unsigned)(u >= 0xFFFF0000u);
        }
        if (!bad) break;
      }
      *(uint4*)&hlds[srow][sc32]      = v0;
      *(uint4*)&hlds[srow][sc32 + 8]  = v1;
      *(uint4*)&hlds[srow][sc32 + 16] = v2;
      *(uint4*)&hlds[srow][sc32 + 24] = v3;
    }
    __syncthreads();
    // --- prefetch xp for step s+1 (overlaps MFMA+epilogue; retired by the
    //     time the next poll's vmcnt(0) runs) ---
    float xn0=0.f, xn1=0.f, xn2=0.f, xn3=0.f;
    {
      int sp = (s < 1023) ? s+1 : 1023;
      if (l < 32){
        xn0 = bf2f(XP[(sp*64 + bi + (l>>4)*4 + 0)*1024 + ecol]);
        xn1 = bf2f(XP[(sp*64 + bi + (l>>4)*4 + 1)*1024 + ecol]);
        xn2 = bf2f(XP[(sp*64 + bi + (l>>4)*4 + 2)*1024 + ecol]);
        xn3 = bf2f(XP[(sp*64 + bi + (l>>4)*4 + 3)*1024 + ecol]);
      }
    }
    // --- 32 MFMA, 4 independent chains ---
    const int arow = (l&15)&7;
    fx4 ac0 = {0.f,0.f,0.f,0.f}, ac1 = ac0, ac2 = ac0, ac3 = ac0;
    #pragma unroll
    for (int kk=0;kk<32;kk+=4){
      s16x8 a0 = *(const s16x8*)&hlds[arow][(kk+0)*32 + kbase];
      s16x8 a1 = *(const s16x8*)&hlds[arow][(kk+1)*32 + kbase];
      s16x8 a2 = *(const s16x8*)&hlds[arow][(kk+2)*32 + kbase];
      s16x8 a3 = *(const s16x8*)&hlds[arow][(kk+3)*32 + kbase];
      ac0 = __builtin_amdgcn_mfma_f32_16x16x32_bf16(a0, wf[kk+0], ac0, 0,0,0);
      ac1 = __builtin_amdgcn_mfma_f32_16x16x32_bf16(a1, wf[kk+1], ac1, 0,0,0);
      ac2 = __builtin_amdgcn_mfma_f32_16x16x32_bf16(a2, wf[kk+2], ac2, 0,0,0);
      ac3 = __builtin_amdgcn_mfma_f32_16x16x32_bf16(a3, wf[kk+3], ac3, 0,0,0);
    }
    fx4 acc = (ac0+ac1)+(ac2+ac3);
    // --- epilogue: h_s = tanh(acc + xp_cur), sc1 stores (self-announcing) ---
    if (l < 32){
      int rbase = (l>>4)*4;
      unsigned short h0 = f2bf(tanh_fast(acc[0] + xc0));
      unsigned short h1 = f2bf(tanh_fast(acc[1] + xc1));
      unsigned short h2 = f2bf(tanh_fast(acc[2] + xc2));
      unsigned short h3 = f2bf(tanh_fast(acc[3] + xc3));
      __hip_atomic_store(&HS[((bi+rbase+0)*1024 + s)*1024 + ecol], h0,
                         __ATOMIC_RELAXED, __HIP_MEMORY_SCOPE_AGENT);
      __hip_atomic_store(&HS[((bi+rbase+1)*1024 + s)*1024 + ecol], h1,
                         __ATOMIC_RELAXED, __HIP_MEMORY_SCOPE_AGENT);
      __hip_atomic_store(&HS[((bi+rbase+2)*1024 + s)*1024 + ecol], h2,
                         __ATOMIC_RELAXED, __HIP_MEMORY_SCOPE_AGENT);
      __hip_atomic_store(&HS[((bi+rbase+3)*1024 + s)*1024 + ecol], h3,
                         __ATOMIC_RELAXED, __HIP_MEMORY_SCOPE_AGENT);
    }
    xc0 = xn0; xc1 = xn1; xc2 = xn2; xc3 = xn3;
    // no drain/flag/trailing barrier: next step's poll provides ordering.
  }
}

// ---------------------------------------------------------------- GEMM2: out = hs@W_out^T + b_out
__global__ __launch_bounds__(512) void k_gemm_out(
    const unsigned short* __restrict__ HS, const unsigned short* __restrict__ WoutB,
    const float* __restrict__ bout, float* __restrict__ OUT){
  __shared__ unsigned short As[128][40];
  __shared__ unsigned short Bs[512][40];
  const int m0 = blockIdx.x*128;
  const int tid = threadIdx.x, w = tid>>6, l = tid&63;
  const int wm = w>>2, wn = w&3;
  fx4 acc[4][8] = {};
  for (int kb = 0; kb < 1024; kb += 32){
    {
      int row = tid>>2, c8 = (tid&3)*8;
      *(uint4*)&As[row][c8] = *(const uint4*)(HS + (m0+row)*1024 + kb + c8);
    }
    #pragma unroll
    for (int q=0;q<4;q++){
      int f = tid + q*512;
      int row = f>>2, c8 = (f&3)*8;
      *(uint4*)&Bs[row][c8] = *(const uint4*)(WoutB + row*1024 + kb + c8);
    }
    __syncthreads();
    const int kbase = (l>>4)*8;
    s16x8 a[4], b[8];
    #pragma unroll
    for (int mt=0;mt<4;mt++) a[mt] = *(const s16x8*)&As[wm*64 + mt*16 + (l&15)][kbase];
    #pragma unroll
    for (int nt=0;nt<8;nt++) b[nt] = *(const s16x8*)&Bs[wn*128 + nt*16 + (l&15)][kbase];
    #pragma unroll
    for (int mt=0;mt<4;mt++)
      #pragma unroll
      for (int nt=0;nt<8;nt++)
        acc[mt][nt] = __builtin_amdgcn_mfma_f32_16x16x32_bf16(a[mt], b[nt], acc[mt][nt], 0,0,0);
    __syncthreads();
  }
  #pragma unroll
  for (int nt=0;nt<8;nt++){
    int n = wn*128 + nt*16 + (l&15);
    float bias = bout[n];
    #pragma unroll
    for (int mt=0;mt<4;mt++){
      #pragma unroll
      for (int r=0;r<4;r++){
        int row = m0 + wm*64 + mt*16 + (l>>4)*4 + r;
        OUT[row*512 + n] = acc[mt][nt][r] + bias;
      }
    }
  }
}

// ---------------------------------------------------------------- launch
extern "C" void kernel_launch(void* const* d_in, const int* in_sizes, int n_in,
                              void* d_out, int out_size, void* d_ws, size_t ws_size,
                              hipStream_t stream){
  const float* x    = (const float*)d_in[0];
  const float* Wih  = (const float*)d_in[1];
  const float* Whh  = (const float*)d_in[2];
  const float* bih  = (const float*)d_in[3];
  const float* bhh  = (const float*)d_in[4];
  const float* Wout = (const float*)d_in[5];
  const float* bout = (const float*)d_in[6];

  const size_t XP_BYTES = 134217728ull;            // bf16 xp, [T][B][H]
  unsigned short* XP    = (unsigned short*)d_ws;
  unsigned short* WoutB = (unsigned short*)((char*)d_ws + XP_BYTES);
  unsigned short* HS    = (unsigned short*)d_out;  // hs bf16 lives in d_out
  float*          OUT   = (float*)d_out;

  k_cvt_wout<<<512, 256, 0, stream>>>(Wout, WoutB);
  dim3 g1(512, 8);
  k_gemm_xp<<<g1, 256, 0, stream>>>(x, Wih, bih, bhh, XP);
  // poison HS: 0xFF bytes -> every bf16 short is NaN (0xFFFF); tanh output
  // can never be NaN, so non-poison == final value (self-announcing data).
  hipMemsetAsync(HS, 0xFF, 134217728ull, stream);
  k_rnn<<<64, 512, 0, stream>>>(Whh, XP, HS);
  k_gemm_out<<<512, 512, 0, stream>>>(HS, WoutB, bout, OUT);
}

// Round 12
// 2706.132 us; speedup vs baseline: 2.4970x; 2.4970x over previous
//
#include <hip/hip_runtime.h>

typedef __attribute__((ext_vector_type(8))) short s16x8;
typedef __attribute__((ext_vector_type(4))) float fx4;

static __device__ __forceinline__ unsigned short f2bf(float f){
  unsigned u = __float_as_uint(f);
  return (unsigned short)((u + 0x7fffu + ((u>>16)&1u)) >> 16);   // RNE
}
static __device__ __forceinline__ float bf2f(unsigned short s){
  return __uint_as_float(((unsigned)s)<<16);
}
// fast tanh: 1 - 2/(e^{2x}+1). Saturates to +-1, error ~1e-6 << bf16 ulp,
// can NEVER produce NaN (poison-safe). ~6 VALU ops vs libm tanhf's ~60.
static __device__ __forceinline__ float tanh_fast(float x){
  float e = __expf(2.0f*x);
  return 1.0f - 2.0f*__builtin_amdgcn_rcpf(e + 1.0f);
}
// Two 16B LLC-point loads (sc0+sc1 = agent scope: bypass L1 AND L2, read the
// LLC). asm volatile + memory clobber => re-executed every poll iteration.
// R4-R11 lessons: cross-XCD data is only HW-coherent at the LLC; polled
// addresses must be re-read at the LLC each iteration; validity must live IN
// the data (poison), not a separate flag; and poll pressure must be kept
// MINIMAL (R11: wider chunks + tighter spin -> LLC contention -> 2.5x slower).
static __device__ __forceinline__ void ld2_llc(const void* p0, const void* p1,
                                               uint4* o0, uint4* o1){
  uint4 a, b;
  asm volatile("global_load_dwordx4 %0, %2, off sc0 sc1\n\t"
               "global_load_dwordx4 %1, %3, off sc0 sc1\n\t"
               "s_waitcnt vmcnt(0)"
               : "=&v"(a), "=&v"(b) : "v"(p0), "v"(p1) : "memory");
  *o0 = a; *o1 = b;
}

// ---------------------------------------------------------------- W_out -> bf16
__global__ void k_cvt_wout(const float* __restrict__ w, unsigned short* __restrict__ o){
  int g = blockIdx.x*256 + threadIdx.x;
  int idx = g*4;
  float4 f = *(const float4*)(w + idx);
  unsigned u0 = (unsigned)f2bf(f.x) | ((unsigned)f2bf(f.y)<<16);
  unsigned u1 = (unsigned)f2bf(f.z) | ((unsigned)f2bf(f.w)<<16);
  *(uint2*)(o + idx) = make_uint2(u0, u1);
}

// ---------------------------------------------------------------- GEMM1: xp = x@W_ih^T + (b_ih+b_hh)
__global__ __launch_bounds__(256) void k_gemm_xp(
    const float* __restrict__ X, const float* __restrict__ Wih,
    const float* __restrict__ bih, const float* __restrict__ bhh,
    unsigned short* __restrict__ XP){
  __shared__ unsigned short As[128][40];
  __shared__ unsigned short Bs[128][40];
  const int bm = blockIdx.x, bn = blockIdx.y;
  const int tid = threadIdx.x, w = tid>>6, l = tid&63;
  const int wm = w>>1, wn = w&1;
  const int m0 = bm*128, n0 = bn*128;
  fx4 acc[4][4] = {};
  for (int kb = 0; kb < 512; kb += 32){
    #pragma unroll
    for (int q=0;q<4;q++){
      int f = tid + q*256;
      int row = f>>3, c4 = (f&7)*4;
      float4 v = *(const float4*)(X + (m0+row)*512 + kb + c4);
      unsigned u0 = (unsigned)f2bf(v.x) | ((unsigned)f2bf(v.y)<<16);
      unsigned u1 = (unsigned)f2bf(v.z) | ((unsigned)f2bf(v.w)<<16);
      *(uint2*)&As[row][c4] = make_uint2(u0,u1);
    }
    #pragma unroll
    for (int q=0;q<4;q++){
      int f = tid + q*256;
      int row = f>>3, c4 = (f&7)*4;
      float4 v = *(const float4*)(Wih + (n0+row)*512 + kb + c4);
      unsigned u0 = (unsigned)f2bf(v.x) | ((unsigned)f2bf(v.y)<<16);
      unsigned u1 = (unsigned)f2bf(v.z) | ((unsigned)f2bf(v.w)<<16);
      *(uint2*)&Bs[row][c4] = make_uint2(u0,u1);
    }
    __syncthreads();
    const int kbase = (l>>4)*8;
    s16x8 a[4], b[4];
    #pragma unroll
    for (int mt=0;mt<4;mt++) a[mt] = *(const s16x8*)&As[wm*64 + mt*16 + (l&15)][kbase];
    #pragma unroll
    for (int nt=0;nt<4;nt++) b[nt] = *(const s16x8*)&Bs[wn*64 + nt*16 + (l&15)][kbase];
    #pragma unroll
    for (int mt=0;mt<4;mt++)
      #pragma unroll
      for (int nt=0;nt<4;nt++)
        acc[mt][nt] = __builtin_amdgcn_mfma_f32_16x16x32_bf16(a[mt], b[nt], acc[mt][nt], 0,0,0);
    __syncthreads();
  }
  #pragma unroll
  for (int nt=0;nt<4;nt++){
    int n = n0 + wn*64 + nt*16 + (l&15);
    float bias = bih[n] + bhh[n];
    #pragma unroll
    for (int mt=0;mt<4;mt++){
      #pragma unroll
      for (int r=0;r<4;r++){
        int grow = m0 + wm*64 + mt*16 + (l>>4)*4 + r;   // = b*1024 + t
        int bb = grow >> 10, t = grow & 1023;
        XP[(t*64 + bb)*1024 + n] = f2bf(acc[mt][nt][r] + bias);
      }
    }
  }
}

// ---------------------------------------------------------------- recurrence
// R9 poison-poll protocol FROZEN (best measured 2540us). Two strictly-local
// additions that do not touch poll structure, pacing, or store pattern:
//  (1) SELF-CHUNK BYPASS: the WG produces 128 of the 1024 cols it consumes.
//      Epilogue writes those h values (already in registers) directly into
//      the NEXT step's LDS buffer (double-buffered) and the 64 threads whose
//      staging chunk falls in the own-col range skip polling entirely
//      (-12.5% LLC poll traffic, one fewer producer in every wait set,
//      own data never round-trips the LLC).
//      Race-free by parity: epilogue(s)->buf[s&1]; MFMA(s) reads buf[(s-1)&1];
//      stage(s+1) writes peer chunks of buf[s&1]; barrier covers visibility.
//  (2) tanh_fast in step0 + epilogue (on the serial chain; NaN-free).
// Protocol recap: HS pre-poisoned 0xFFFF (bf16 NaN; tanh can't produce it);
// write-once addresses; sc0+sc1 poll loads re-read the LLC every iteration;
// data self-announces. Placement-independent, flag-free, deadlock-impossible.
__global__ __launch_bounds__(512) void k_rnn(
    const float* __restrict__ Whh, const unsigned short* __restrict__ XP,
    unsigned short* __restrict__ HS){
  __shared__ unsigned short hlds[2][8][1032];
  const int wg = blockIdx.x;
  const int gi = wg & 7;            // batch-group (8 rows)
  const int gj = wg >> 3;           // col block (128 cols)
  const int bi = gi*8, cj = gj*128;
  const int tid = threadIdx.x, w = tid>>6, l = tid&63;
  const int kbase = (l>>4)*8;

  // --- W_hh slice as resident MFMA B-fragments (128 VGPR/lane) ---
  const int col = cj + w*16 + (l&15);
  s16x8 wf[32];
  #pragma unroll
  for (int kk=0; kk<32; kk++){
    const float* p = Whh + col*1024 + kk*32 + kbase;
    float4 v0 = *(const float4*)p;
    float4 v1 = *(const float4*)(p+4);
    s16x8 s;
    s[0]=(short)f2bf(v0.x); s[1]=(short)f2bf(v0.y); s[2]=(short)f2bf(v0.z); s[3]=(short)f2bf(v0.w);
    s[4]=(short)f2bf(v1.x); s[5]=(short)f2bf(v1.y); s[6]=(short)f2bf(v1.z); s[7]=(short)f2bf(v1.w);
    wf[kk]=s;
  }

  const int ecol = cj + w*16 + (l&15);

  // --- step 0: h0 = tanh(xp_0); store global (self-announcing) + LDS buf0 ---
  {
    int e = tid*2;
    int row = e>>7, c = e&127;
    unsigned short h0 = f2bf(tanh_fast(bf2f(XP[(bi+row)*1024 + cj + c])));
    unsigned short h1 = f2bf(tanh_fast(bf2f(XP[(bi+row)*1024 + cj + c + 1])));
    unsigned pk = (unsigned)h0 | ((unsigned)h1<<16);
    __hip_atomic_store((unsigned*)&HS[((bi+row)*1024 + 0)*1024 + cj + c], pk,
                       __ATOMIC_RELAXED, __HIP_MEMORY_SCOPE_AGENT);
    hlds[0][row][cj + c]     = h0;       // own chunk pre-staged for step 1
    hlds[0][row][cj + c + 1] = h1;
  }

  const int srow = tid>>6, sc8 = (tid&63)*16;       // staging: thread owns (row, 32B)
  const bool ownchunk = ((unsigned)(sc8 - cj) < 128u); // chunk lies in own cols

  for (int s=1; s<1024; ++s){
    // xp prefetch (R9 position: before poll, consumed in epilogue)
    float xv[4];
    if (l < 32){
      #pragma unroll
      for (int r=0;r<4;r++)
        xv[r] = bf2f(XP[(s*64 + bi + (l>>4)*4 + r)*1024 + ecol]);
    }
    unsigned short (*buf)[1032]  = hlds[(s-1)&1];   // holds h_{s-1}
    unsigned short (*nbuf)[1032] = hlds[s&1];       // receives own h_s
    // --- poison-poll + stage h_{s-1}: peer chunks only (own pre-staged) ---
    if (!ownchunk){
      const unsigned short* rowp = HS + ((bi+srow)*1024 + (s-1))*1024 + sc8;
      uint4 v0, v1;
      for(;;){
        ld2_llc(rowp, rowp+8, &v0, &v1);
        unsigned bad = 0u;
        #pragma unroll
        for (int j=0;j<4;j++){
          unsigned u = ((unsigned*)&v0)[j];
          bad |= (unsigned)((u & 0xFFFFu) == 0xFFFFu) | (unsigned)(u >= 0xFFFF0000u);
        }
        #pragma unroll
        for (int j=0;j<4;j++){
          unsigned u = ((unsigned*)&v1)[j];
          bad |= (unsigned)((u & 0xFFFFu) == 0xFFFFu) | (unsigned)(u >= 0xFFFF0000u);
        }
        if (!bad) break;
      }
      *(uint4*)&buf[srow][sc8]     = v0;
      *(uint4*)&buf[srow][sc8 + 8] = v1;
    }
    __syncthreads();
    // --- 32 MFMA, 4 independent chains ---
    const int arow = (l&15)&7;
    fx4 ac0 = {0.f,0.f,0.f,0.f}, ac1 = ac0, ac2 = ac0, ac3 = ac0;
    #pragma unroll
    for (int kk=0;kk<32;kk+=4){
      s16x8 a0 = *(const s16x8*)&buf[arow][(kk+0)*32 + kbase];
      s16x8 a1 = *(const s16x8*)&buf[arow][(kk+1)*32 + kbase];
      s16x8 a2 = *(const s16x8*)&buf[arow][(kk+2)*32 + kbase];
      s16x8 a3 = *(const s16x8*)&buf[arow][(kk+3)*32 + kbase];
      ac0 = __builtin_amdgcn_mfma_f32_16x16x32_bf16(a0, wf[kk+0], ac0, 0,0,0);
      ac1 = __builtin_amdgcn_mfma_f32_16x16x32_bf16(a1, wf[kk+1], ac1, 0,0,0);
      ac2 = __builtin_amdgcn_mfma_f32_16x16x32_bf16(a2, wf[kk+2], ac2, 0,0,0);
      ac3 = __builtin_amdgcn_mfma_f32_16x16x32_bf16(a3, wf[kk+3], ac3, 0,0,0);
    }
    fx4 acc = (ac0+ac1)+(ac2+ac3);
    // --- epilogue: h_s = tanh(acc + xp); sc1 store (self-announcing) +
    //     own-chunk write into next step's LDS buffer ---
    if (l < 32){
      #pragma unroll
      for (int r=0;r<4;r++){
        int row = (l>>4)*4 + r;
        unsigned short hv = f2bf(tanh_fast(acc[r] + xv[r]));
        __hip_atomic_store(&HS[((bi+row)*1024 + s)*1024 + ecol], hv,
                           __ATOMIC_RELAXED, __HIP_MEMORY_SCOPE_AGENT);
        nbuf[row][ecol] = hv;
      }
    }
    // no drain/flag/trailing barrier: next step's poll + barrier order it.
  }
}

// ---------------------------------------------------------------- GEMM2: out = hs@W_out^T + b_out
__global__ __launch_bounds__(512) void k_gemm_out(
    const unsigned short* __restrict__ HS, const unsigned short* __restrict__ WoutB,
    const float* __restrict__ bout, float* __restrict__ OUT){
  __shared__ unsigned short As[128][40];
  __shared__ unsigned short Bs[512][40];
  const int m0 = blockIdx.x*128;
  const int tid = threadIdx.x, w = tid>>6, l = tid&63;
  const int wm = w>>2, wn = w&3;
  fx4 acc[4][8] = {};
  for (int kb = 0; kb < 1024; kb += 32){
    {
      int row = tid>>2, c8 = (tid&3)*8;
      *(uint4*)&As[row][c8] = *(const uint4*)(HS + (m0+row)*1024 + kb + c8);
    }
    #pragma unroll
    for (int q=0;q<4;q++){
      int f = tid + q*512;
      int row = f>>2, c8 = (f&3)*8;
      *(uint4*)&Bs[row][c8] = *(const uint4*)(WoutB + row*1024 + kb + c8);
    }
    __syncthreads();
    const int kbase = (l>>4)*8;
    s16x8 a[4], b[8];
    #pragma unroll
    for (int mt=0;mt<4;mt++) a[mt] = *(const s16x8*)&As[wm*64 + mt*16 + (l&15)][kbase];
    #pragma unroll
    for (int nt=0;nt<8;nt++) b[nt] = *(const s16x8*)&Bs[wn*128 + nt*16 + (l&15)][kbase];
    #pragma unroll
    for (int mt=0;mt<4;mt++)
      #pragma unroll
      for (int nt=0;nt<8;nt++)
        acc[mt][nt] = __builtin_amdgcn_mfma_f32_16x16x32_bf16(a[mt], b[nt], acc[mt][nt], 0,0,0);
    __syncthreads();
  }
  #pragma unroll
  for (int nt=0;nt<8;nt++){
    int n = wn*128 + nt*16 + (l&15);
    float bias = bout[n];
    #pragma unroll
    for (int mt=0;mt<4;mt++){
      #pragma unroll
      for (int r=0;r<4;r++){
        int row = m0 + wm*64 + mt*16 + (l>>4)*4 + r;
        OUT[row*512 + n] = acc[mt][nt][r] + bias;
      }
    }
  }
}

// ---------------------------------------------------------------- launch
extern "C" void kernel_launch(void* const* d_in, const int* in_sizes, int n_in,
                              void* d_out, int out_size, void* d_ws, size_t ws_size,
                              hipStream_t stream){
  const float* x    = (const float*)d_in[0];
  const float* Wih  = (const float*)d_in[1];
  const float* Whh  = (const float*)d_in[2];
  const float* bih  = (const float*)d_in[3];
  const float* bhh  = (const float*)d_in[4];
  const float* Wout = (const float*)d_in[5];
  const float* bout = (const float*)d_in[6];

  const size_t XP_BYTES = 134217728ull;            // bf16 xp, [T][B][H]
  unsigned short* XP    = (unsigned short*)d_ws;
  unsigned short* WoutB = (unsigned short*)((char*)d_ws + XP_BYTES);
  unsigned short* HS    = (unsigned short*)d_out;  // hs bf16 lives in d_out
  float*          OUT   = (float*)d_out;

  k_cvt_wout<<<512, 256, 0, stream>>>(Wout, WoutB);
  dim3 g1(512, 8);
  k_gemm_xp<<<g1, 256, 0, stream>>>(x, Wih, bih, bhh, XP);
  // poison HS: 0xFF bytes -> every bf16 short is NaN (0xFFFF); tanh output
  // can never be NaN, so non-poison == final value (self-announcing data).
  hipMemsetAsync(HS, 0xFF, 134217728ull, stream);
  k_rnn<<<64, 512, 0, stream>>>(Whh, XP, HS);
  k_gemm_out<<<512, 512, 0, stream>>>(HS, WoutB, bout, OUT);
}